// Round 7
// baseline (581.095 us; speedup 1.0000x reference)
//
#include <hip/hip_runtime.h>
#include <hip/hip_bf16.h>

// GraphSAGE(max) x3 + two heads on MI355X.
// R7: XCD-sliced aggregation. Random gather amplified FETCH to ~7x table size
//     (each XCD pulls the whole 25.6MB table via its 4MB L2). Max decomposes
//     per-column -> slice columns 64B-wide, slice = blockIdx % NSLICE; linear
//     block->XCD dispatch is round-robin so each XCD's gather footprint is
//     one slice = 3.2MB (L2-resident).
// edge_index arrives as int32 [2,E]: src = ei[e], dst = ei[NE + e].

#define NN 50000
#define NE 800000
#define HD 256
#define CAP 64  // bucket capacity; Poisson(16) tail P(>=64) ~ 2e-18/node

using bf16 = __hip_bfloat16;
typedef float f32x4 __attribute__((ext_vector_type(4)));
typedef short bf16x8 __attribute__((ext_vector_type(8)));

__device__ __forceinline__ void async16(const void* g, void* l) {
    __builtin_amdgcn_global_load_lds(
        (const __attribute__((address_space(1))) unsigned int*)g,
        (__attribute__((address_space(3))) unsigned int*)l, 16, 0, 0);
}

__device__ __forceinline__ unsigned short f2b(float f) {
    bf16 b = __float2bfloat16(f);
    return __builtin_bit_cast(unsigned short, b);
}

// ---------------- CSR build: one atomic-append pass ----------------
__global__ void k_scatter(const int* __restrict__ ei, int* __restrict__ cnt,
                          int* __restrict__ srcp) {
    int e = blockIdx.x * 256 + threadIdx.x;
    if (e < NE) {
        int d = ei[NE + e];
        int slot = atomicAdd(&cnt[d], 1);
        if (slot < CAP) srcp[(d << 6) + slot] = ei[e];  // src row
    }
}

// ---------------- merged prep: cvt_x | pack weights | zero cnt ------------
__device__ __forceinline__ void pack1(const float* __restrict__ W,
                                      bf16* __restrict__ bt, int idx, int Ktot,
                                      int kofs) {
    int k = idx >> 8, n = idx & 255;
    bt[(size_t)n * Ktot + kofs + k] = __float2bfloat16(W[idx]);
}

#define PREP_CVT_B 6250   // NN*128/4/256
#define PREP_PACK_B 1792  // 458752/256
#define PREP_CNT_B 196    // NN/256
#define PREP_B (PREP_CVT_B + PREP_PACK_B + PREP_CNT_B)

__global__ void k_prep(const float* __restrict__ x, bf16* __restrict__ xb,
                       const float* __restrict__ Wl1,
                       const float* __restrict__ Wr1,
                       const float* __restrict__ Wl2,
                       const float* __restrict__ Wr2,
                       const float* __restrict__ Wla,
                       const float* __restrict__ Wra,
                       const float* __restrict__ Wlm,
                       const float* __restrict__ Wrm, bf16* __restrict__ Bt1,
                       bf16* __restrict__ Bt2, bf16* __restrict__ Bta,
                       bf16* __restrict__ Btm, int* __restrict__ cnt) {
    int b = blockIdx.x;
    if (b < PREP_CVT_B) {
        int i = b * 256 + threadIdx.x;  // < 1.6M exactly
        float4 v = ((const float4*)x)[i];
        ushort4 o;
        o.x = f2b(v.x); o.y = f2b(v.y); o.z = f2b(v.z); o.w = f2b(v.w);
        ((ushort4*)xb)[i] = o;
    } else if (b < PREP_CVT_B + PREP_PACK_B) {
        int idx = (b - PREP_CVT_B) * 256 + threadIdx.x;  // < 458752 exactly
        if (idx < 32768) pack1(Wl1, Bt1, idx, 256, 0);
        else if (idx < 65536) pack1(Wr1, Bt1, idx - 32768, 256, 128);
        else if (idx < 131072) pack1(Wl2, Bt2, idx - 65536, 512, 0);
        else if (idx < 196608) pack1(Wr2, Bt2, idx - 131072, 512, 256);
        else if (idx < 262144) pack1(Wla, Bta, idx - 196608, 512, 0);
        else if (idx < 327680) pack1(Wra, Bta, idx - 262144, 512, 256);
        else if (idx < 393216) pack1(Wlm, Btm, idx - 327680, 512, 0);
        else pack1(Wrm, Btm, idx - 393216, 512, 256);
    } else {
        int i = (b - PREP_CVT_B - PREP_PACK_B) * 256 + threadIdx.x;
        if (i < NN) cnt[i] = 0;
    }
}

// ------------- XCD-sliced segment-max aggregation -------------------------
// Slice = 32 cols (64 B). slice = blockIdx % NSLICE; with linear round-robin
// block->XCD dispatch each XCD's feature footprint is one slice (3.2 MB,
// L2-resident). A wave: 4 lane-groups of 16, each group gathers one edge's
// 64 B slice; groups interleave over the node's edge list; cross-group
// shfl-max at the end. NSLICE=8 for F=256, 4 for F=128.
template <int NSLICE>
__global__ __launch_bounds__(256) void k_agg_sl(const bf16* __restrict__ feat,
                                                bf16* __restrict__ agg,
                                                const int* __restrict__ cnt,
                                                const int* __restrict__ srcp) {
    const int FU = NSLICE * 16;  // row stride in uints (2 bf16 each)
    int b = blockIdx.x;
    int slice = b & (NSLICE - 1);
    int node = (b / NSLICE) * 4 + (threadIdx.x >> 6);
    if (node >= NN) return;
    int lane = threadIdx.x & 63;
    int g = lane >> 4, cc = lane & 15;
    int n = min(cnt[node], CAP);
    const int* __restrict__ lst = srcp + (node << 6);
    const unsigned* __restrict__ fp = (const unsigned*)feat + slice * 16 + cc;

    float m0 = __int_as_float(0xff800000), m1 = m0;  // -inf
    int e = g;
    for (; e + 4 < n; e += 8) {  // 2 independent gathers in flight per lane
        int sa = lst[e], sb = lst[e + 4];
        unsigned va = fp[(size_t)sa * FU];
        unsigned vb = fp[(size_t)sb * FU];
        m0 = fmaxf(m0, __uint_as_float(va << 16));
        m1 = fmaxf(m1, __uint_as_float(va & 0xffff0000u));
        m0 = fmaxf(m0, __uint_as_float(vb << 16));
        m1 = fmaxf(m1, __uint_as_float(vb & 0xffff0000u));
    }
    if (e < n) {
        int s = lst[e];
        unsigned v = fp[(size_t)s * FU];
        m0 = fmaxf(m0, __uint_as_float(v << 16));
        m1 = fmaxf(m1, __uint_as_float(v & 0xffff0000u));
    }
    // cross-group max: groups handled interleaved edges of the same node
    m0 = fmaxf(m0, __shfl_xor(m0, 16, 64));
    m0 = fmaxf(m0, __shfl_xor(m0, 32, 64));
    m1 = fmaxf(m1, __shfl_xor(m1, 16, 64));
    m1 = fmaxf(m1, __shfl_xor(m1, 32, 64));
    if (g == 0) {
        // isolated node -> 0 (reference: where(agg <= finfo.min, 0, agg))
        unsigned r = 0;
        if (n > 0)
            r = (__float_as_uint(m0) >> 16) |
                (__float_as_uint(m1) & 0xffff0000u);
        ((unsigned*)agg)[(size_t)node * FU + slice * 16 + cc] = r;
    }
}

// ------- MFMA GEMM core (128 rows x 256 cols): acc = [A0|A1] @ Bt^T -------
// Wave w: rows [(w>>1)*64, +64), cols [(w&1)*128, +128). acc[4][8].
__device__ __forceinline__ void gemm_core256(const bf16* __restrict__ A0,
                                             const bf16* __restrict__ A1, int F,
                                             int Ktot,
                                             const bf16* __restrict__ Bt,
                                             int bm0, int t, short* As,
                                             short* Bs, f32x4 (&acc)[4][8]) {
    const int wave = t >> 6;
    const int lane = t & 63;
    const int q = lane >> 4;
    const int c = lane & 15;
    const int wr = (wave >> 1) * 64;
    const int wcl = (wave & 1) * 128;

    for (int k0 = 0; k0 < Ktot; k0 += 64) {
        const bf16* Asrc = (k0 < F) ? A0 : A1;
        const int kk = (k0 < F) ? k0 : k0 - F;
        __syncthreads();
        // stage A tile [128 rows][64 k]: XOR-swizzled k-chunks (swizzle applied
        // to global addr so global_load_lds's lane-linear LDS layout holds)
#pragma unroll
        for (int it = 0; it < 4; ++it) {
            int chunk = it * 256 + t;
            int row = chunk >> 3, kc = chunk & 7;
            int kcg = kc ^ (row & 7);
            int grow = bm0 + row;
            if (grow > NN - 1) grow = NN - 1;
            async16(Asrc + (size_t)grow * F + kk + kcg * 8, &As[chunk * 8]);
        }
        // stage B tile [256 n][64 k]
#pragma unroll
        for (int it = 0; it < 8; ++it) {
            int chunk = it * 256 + t;
            int row = chunk >> 3, kc = chunk & 7;
            int kcg = kc ^ (row & 7);
            async16(Bt + (size_t)row * Ktot + k0 + kcg * 8, &Bs[chunk * 8]);
        }
        __syncthreads();
#pragma unroll
        for (int ks = 0; ks < 2; ++ks) {
            bf16x8 af[4], bfr[8];
            int ch = (ks * 4 + q) ^ (c & 7);
#pragma unroll
            for (int i = 0; i < 4; ++i)
                af[i] = *(const bf16x8*)&As[(wr + i * 16 + c) * 64 + ch * 8];
#pragma unroll
            for (int j = 0; j < 8; ++j)
                bfr[j] = *(const bf16x8*)&Bs[(wcl + j * 16 + c) * 64 + ch * 8];
#pragma unroll
            for (int i = 0; i < 4; ++i)
#pragma unroll
                for (int j = 0; j < 8; ++j)
                    acc[i][j] = __builtin_amdgcn_mfma_f32_16x16x32_bf16(
                        af[i], bfr[j], acc[i][j], 0, 0, 0);
        }
    }
}

// hidden-layer GEMM: Hout[row,col] = bf16(relu(acc + bias[col]))
__global__ __launch_bounds__(256, 2) void k_gemm_h(
    const bf16* __restrict__ A0, const bf16* __restrict__ A1, int F, int Ktot,
    const bf16* __restrict__ Bt, const float* __restrict__ bias,
    bf16* __restrict__ Hout) {
    __shared__ __attribute__((aligned(16))) short As[128 * 64];
    __shared__ __attribute__((aligned(16))) short Bs[256 * 64];
    const int t = threadIdx.x;
    const int bm0 = blockIdx.x * 128;
    const int wave = t >> 6;
    const int lane = t & 63;
    const int q = lane >> 4;
    const int c = lane & 15;
    const int wr = (wave >> 1) * 64;
    const int wcl = (wave & 1) * 128;

    f32x4 acc[4][8];
#pragma unroll
    for (int i = 0; i < 4; ++i)
#pragma unroll
        for (int j = 0; j < 8; ++j) acc[i][j] = (f32x4){0.f, 0.f, 0.f, 0.f};
    gemm_core256(A0, A1, F, Ktot, Bt, bm0, t, As, Bs, acc);

    float bcol[8];
#pragma unroll
    for (int j = 0; j < 8; ++j) bcol[j] = bias[wcl + j * 16 + c];
#pragma unroll
    for (int i = 0; i < 4; ++i)
#pragma unroll
        for (int r = 0; r < 4; ++r) {
            int row = bm0 + wr + i * 16 + q * 4 + r;  // C/D: row=quad*4+reg
            if (row < NN) {
#pragma unroll
                for (int j = 0; j < 8; ++j) {
                    int col = wcl + j * 16 + c;  // C/D: col=lane&15
                    float v = fmaxf(acc[i][j][r] + bcol[j], 0.f);
                    Hout[(size_t)row * HD + col] = __float2bfloat16(v);
                }
            }
        }
}

// head GEMM (blockIdx.y: 0=rtang, 1=movedis):
// out[z*NN+row] = hb + sum_col relu(acc + bias[col]) * Wh[col]  (direct store)
__global__ __launch_bounds__(256, 2) void k_gemm_heads(
    const bf16* __restrict__ A0, const bf16* __restrict__ A1,
    const bf16* __restrict__ Bta, const float* __restrict__ bla,
    const float* __restrict__ Wa, const float* __restrict__ ba,
    const bf16* __restrict__ Btm, const float* __restrict__ blm,
    const float* __restrict__ Wm, const float* __restrict__ bm,
    float* __restrict__ out) {
    __shared__ __attribute__((aligned(16))) short As[128 * 64];
    __shared__ __attribute__((aligned(16))) short Bs[256 * 64];
    const int t = threadIdx.x;
    const int bm0 = blockIdx.x * 128;
    const int z = blockIdx.y;
    const bf16* Bt = z ? Btm : Bta;
    const float* bias = z ? blm : bla;
    const float* Wh = z ? Wm : Wa;
    const float hb = z ? bm[0] : ba[0];
    float* outp = out + (size_t)z * NN;
    const int wave = t >> 6;
    const int lane = t & 63;
    const int q = lane >> 4;
    const int c = lane & 15;
    const int wr = (wave >> 1) * 64;
    const int wcl = (wave & 1) * 128;

    f32x4 acc[4][8];
#pragma unroll
    for (int i = 0; i < 4; ++i)
#pragma unroll
        for (int j = 0; j < 8; ++j) acc[i][j] = (f32x4){0.f, 0.f, 0.f, 0.f};
    gemm_core256(A0, A1, 256, 512, Bt, bm0, t, As, Bs, acc);

    float bcol[8], wcol[8];
#pragma unroll
    for (int j = 0; j < 8; ++j) {
        int col = wcl + j * 16 + c;
        bcol[j] = bias[col];
        wcol[j] = Wh[col];
    }
    // per-(i,r) partial dot over this wave's 128 cols
    float pr[4][4];
#pragma unroll
    for (int i = 0; i < 4; ++i)
#pragma unroll
        for (int r = 0; r < 4; ++r) {
            float p = 0.f;
#pragma unroll
            for (int j = 0; j < 8; ++j)
                p += fmaxf(acc[i][j][r] + bcol[j], 0.f) * wcol[j];
            p += __shfl_xor(p, 1, 64);
            p += __shfl_xor(p, 2, 64);
            p += __shfl_xor(p, 4, 64);
            p += __shfl_xor(p, 8, 64);
            pr[i][r] = p;  // valid at c==0 lanes
        }
    // cross-wave pair (w, w^1) share rows, cover cols 0-127 / 128-255
    __syncthreads();
    float* red = (float*)As;
    if ((wave & 1) && c == 0) {
#pragma unroll
        for (int i = 0; i < 4; ++i)
#pragma unroll
            for (int r = 0; r < 4; ++r) red[wr + i * 16 + q * 4 + r] = pr[i][r];
    }
    __syncthreads();
    if (!(wave & 1) && c == 0) {
#pragma unroll
        for (int i = 0; i < 4; ++i)
#pragma unroll
            for (int r = 0; r < 4; ++r) {
                int lr = wr + i * 16 + q * 4 + r;
                int row = bm0 + lr;
                if (row < NN) outp[row] = pr[i][r] + red[lr] + hb;
            }
    }
}

extern "C" void kernel_launch(void* const* d_in, const int* in_sizes, int n_in,
                              void* d_out, int out_size, void* d_ws,
                              size_t ws_size, hipStream_t stream) {
    const float* x = (const float*)d_in[0];
    const int* ei = (const int*)d_in[1];  // int32 [2,E]
    const float* Wl1 = (const float*)d_in[2];
    const float* bl1 = (const float*)d_in[3];
    const float* Wr1 = (const float*)d_in[4];
    const float* Wl2 = (const float*)d_in[5];
    const float* bl2 = (const float*)d_in[6];
    const float* Wr2 = (const float*)d_in[7];
    const float* Wla = (const float*)d_in[8];
    const float* bla = (const float*)d_in[9];
    const float* Wra = (const float*)d_in[10];
    const float* Wa = (const float*)d_in[11];
    const float* ba = (const float*)d_in[12];
    const float* Wlm = (const float*)d_in[13];
    const float* blm = (const float*)d_in[14];
    const float* Wrm = (const float*)d_in[15];
    const float* Wm = (const float*)d_in[16];
    const float* bm = (const float*)d_in[17];
    float* out = (float*)d_out;

    char* ws = (char*)d_ws;
    size_t off = 0;
    auto alloc = [&](size_t b) {
        void* p = ws + off;
        off = (off + b + 255) & ~(size_t)255;
        return p;
    };
    int* srcp = (int*)alloc((size_t)NN * CAP * 4);
    int* cnt = (int*)alloc((size_t)NN * 4);
    bf16* xb = (bf16*)alloc((size_t)NN * 128 * 2);
    bf16* h1 = (bf16*)alloc((size_t)NN * 256 * 2);
    bf16* h2 = (bf16*)alloc((size_t)NN * 256 * 2);
    bf16* agg = (bf16*)alloc((size_t)NN * 256 * 2);
    bf16* Bt1 = (bf16*)alloc((size_t)256 * 256 * 2);
    bf16* Bt2 = (bf16*)alloc((size_t)256 * 512 * 2);
    bf16* Bta = (bf16*)alloc((size_t)256 * 512 * 2);
    bf16* Btm = (bf16*)alloc((size_t)256 * 512 * 2);
    (void)ws_size; (void)in_sizes; (void)n_in; (void)out_size;

    // prep (cvt_x | pack weights | zero cnt), then bucket CSR
    k_prep<<<PREP_B, 256, 0, stream>>>(x, xb, Wl1, Wr1, Wl2, Wr2, Wla, Wra,
                                       Wlm, Wrm, Bt1, Bt2, Bta, Btm, cnt);
    k_scatter<<<(NE + 255) / 256, 256, 0, stream>>>(ei, cnt, srcp);

    const int GB = (NN + 127) / 128;   // 391
    const int NG4 = (NN + 3) / 4;      // 12500 node-groups
    // layer 1 (F=128 -> 4 slices of 64B)
    k_agg_sl<4><<<NG4 * 4, 256, 0, stream>>>(xb, agg, cnt, srcp);
    k_gemm_h<<<GB, 256, 0, stream>>>(agg, xb, 128, 256, Bt1, bl1, h1);
    // layer 2 (F=256 -> 8 slices)
    k_agg_sl<8><<<NG4 * 8, 256, 0, stream>>>(h1, agg, cnt, srcp);
    k_gemm_h<<<GB, 256, 0, stream>>>(agg, h1, 256, 512, Bt2, bl2, h2);
    // layer 3 (shared aggregation) + both heads in one launch (y = head)
    k_agg_sl<8><<<NG4 * 8, 256, 0, stream>>>(h2, agg, cnt, srcp);
    dim3 gh(GB, 2);
    k_gemm_heads<<<gh, 256, 0, stream>>>(agg, h2, Bta, bla, Wa, ba, Btm, blm,
                                         Wm, bm, out);
}